// Round 1
// baseline (977.186 us; speedup 1.0000x reference)
//
#include <hip/hip_runtime.h>

#define N_NODES 100000
#define N_EDGES 600000

// ---------------------------------------------------------------------------
// Fused dual GEMM: outl = x @ wl^T, outr = x @ wr^T   (wl, wr are [F][K])
// Block = 256 threads. OG o-groups; each thread computes NO=2F/OG outputs
// (o = og + OG*i, strided so LDS float4 reads are bank-conflict-free with
// row stride KT+4) for NN=4 nodes. W staged in K-tiles of KT.
// ---------------------------------------------------------------------------
template<int K, int F, int OG, int KT>
__global__ __launch_bounds__(256) void gemm_dual(
    const float* __restrict__ x,
    const float* __restrict__ wl,
    const float* __restrict__ wr,
    float* __restrict__ outl,
    float* __restrict__ outr)
{
    constexpr int TWOF = 2 * F;
    constexpr int NO   = TWOF / OG;   // outputs per thread (4)
    constexpr int NG   = 256 / OG;    // node groups per block
    constexpr int NN   = 4;           // nodes per thread
    constexpr int NPB  = NG * NN;     // nodes per block
    constexpr int WS   = KT + 4;      // padded W row stride (floats), 16B-aligned
    constexpr int NKT  = K / KT;

    __shared__ float Wlds[TWOF * WS];
    __shared__ float xs[NPB * K];

    const int tid = threadIdx.x;
    const int n0  = blockIdx.x * NPB;

    // stage x rows (coalesced global, linear LDS)
    for (int i = tid; i < NPB * K; i += 256) {
        int nr = i / K;
        int k  = i - nr * K;
        int node = n0 + nr;
        xs[i] = (node < N_NODES) ? x[node * K + k] : 0.0f;
    }

    const int og = tid % OG;
    const int ng = tid / OG;

    float acc[NN][NO];
    #pragma unroll
    for (int j = 0; j < NN; ++j)
        #pragma unroll
        for (int i = 0; i < NO; ++i) acc[j][i] = 0.0f;

    for (int kt = 0; kt < NKT; ++kt) {
        const int k0 = kt * KT;
        __syncthreads();
        // stage W tile: rows 0..F-1 from wl, F..2F-1 from wr (cols k0..k0+KT)
        for (int i = tid; i < TWOF * KT; i += 256) {
            int o  = i / KT;
            int kk = i - o * KT;
            float v = (o < F) ? wl[o * K + k0 + kk] : wr[(o - F) * K + k0 + kk];
            Wlds[o * WS + kk] = v;
        }
        __syncthreads();

        #pragma unroll
        for (int k4 = 0; k4 < KT / 4; ++k4) {
            float4 wv[NO];
            #pragma unroll
            for (int i = 0; i < NO; ++i)
                wv[i] = *(const float4*)&Wlds[(og + OG * i) * WS + 4 * k4];
            float4 xv[NN];
            #pragma unroll
            for (int j = 0; j < NN; ++j)
                xv[j] = *(const float4*)&xs[(ng * NN + j) * K + k0 + 4 * k4];
            #pragma unroll
            for (int j = 0; j < NN; ++j) {
                #pragma unroll
                for (int i = 0; i < NO; ++i) {
                    acc[j][i] += xv[j].x * wv[i].x;
                    acc[j][i] += xv[j].y * wv[i].y;
                    acc[j][i] += xv[j].z * wv[i].z;
                    acc[j][i] += xv[j].w * wv[i].w;
                }
            }
        }
    }

    // epilogue (coalesced within o-group)
    #pragma unroll
    for (int j = 0; j < NN; ++j) {
        int node = n0 + ng * NN + j;
        if (node >= N_NODES) continue;
        #pragma unroll
        for (int i = 0; i < NO; ++i) {
            int o = og + OG * i;
            if (o < F) outl[node * F + o] = acc[j][i];
            else       outr[node * F + (o - F)] = acc[j][i];
        }
    }
}

// ---------------------------------------------------------------------------
// Edge scatter: agg[dst] += feat[src] (per float4 chunk), optional degree cnt
// ---------------------------------------------------------------------------
template<int F, bool WITH_CNT>
__global__ __launch_bounds__(256) void scatter_add(
    const float* __restrict__ feat,
    const int* __restrict__ ei,
    float* __restrict__ agg,
    float* __restrict__ cnt)
{
    constexpr int F4 = F / 4;
    int t = blockIdx.x * 256 + threadIdx.x;
    int e = t / F4;
    int q = t - e * F4;
    if (e >= N_EDGES) return;
    int s = ei[e];
    int d = ei[N_EDGES + e];
    float4 v = *(const float4*)&feat[s * F + 4 * q];
    float* a = &agg[d * F + 4 * q];
    atomicAdd(a + 0, v.x);
    atomicAdd(a + 1, v.y);
    atomicAdd(a + 2, v.z);
    atomicAdd(a + 3, v.w);
    if (WITH_CNT && q == 0) atomicAdd(cnt + d, 1.0f);
}

// ---------------------------------------------------------------------------
// out = [relu]( agg/max(cnt,1) + bias + right )
// ---------------------------------------------------------------------------
template<int F, bool RELU>
__global__ __launch_bounds__(256) void finalize_k(
    const float* __restrict__ agg,
    const float* __restrict__ cnt,
    const float* __restrict__ bias,
    const float* __restrict__ right,
    float* __restrict__ out)
{
    constexpr int F4 = F / 4;
    int t = blockIdx.x * 256 + threadIdx.x;
    int n = t / F4;
    int q = t - n * F4;
    if (n >= N_NODES) return;
    float inv = 1.0f / fmaxf(cnt[n], 1.0f);
    float4 a = *(const float4*)&agg[n * F + 4 * q];
    float4 r = *(const float4*)&right[n * F + 4 * q];
    float4 b = *(const float4*)&bias[4 * q];
    float4 o;
    o.x = fmaf(a.x, inv, b.x) + r.x;
    o.y = fmaf(a.y, inv, b.y) + r.y;
    o.z = fmaf(a.z, inv, b.z) + r.z;
    o.w = fmaf(a.w, inv, b.w) + r.w;
    if (RELU) {
        o.x = fmaxf(o.x, 0.0f);
        o.y = fmaxf(o.y, 0.0f);
        o.z = fmaxf(o.z, 0.0f);
        o.w = fmaxf(o.w, 0.0f);
    }
    *(float4*)&out[n * F + 4 * q] = o;
}

extern "C" void kernel_launch(void* const* d_in, const int* in_sizes, int n_in,
                              void* d_out, int out_size, void* d_ws, size_t ws_size,
                              hipStream_t stream)
{
    const float* x   = (const float*)d_in[0];
    const int*   ei  = (const int*)d_in[1];   // int32: JAX x64 disabled -> int64 request yields int32
    const float* w1l = (const float*)d_in[2];
    const float* b1l = (const float*)d_in[3];
    const float* w1r = (const float*)d_in[4];
    const float* w2l = (const float*)d_in[5];
    const float* b2l = (const float*)d_in[6];
    const float* w2r = (const float*)d_in[7];
    float* out = (float*)d_out;

    char* ws = (char*)d_ws;
    // layout (bytes):
    //   [0, 25.6M)        xl  (100000x64 f32)   -> reused as h
    //   [25.6M, 51.2M)    xr  (100000x64 f32)   -> reused as hl (first 12.8M) / hr (second 12.8M)
    //   [51.2M, 76.8M)    agg1 (100000x64 f32)
    //   [76.8M, 89.6M)    agg2 (100000x32 f32)
    //   [89.6M, 90.0M)    cnt  (100000 f32)
    float* xl   = (float*)(ws + 0);
    float* xr   = (float*)(ws + 25600000);
    float* agg1 = (float*)(ws + 51200000);
    float* agg2 = (float*)(ws + 76800000);
    float* cntv = (float*)(ws + 89600000);
    float* h    = xl;                              // overwrite xl after scatter1
    float* hl   = xr;                              // overwrite xr after finalize1
    float* hr   = (float*)(ws + 25600000 + 12800000);

    hipMemsetAsync(agg1, 0, (size_t)N_NODES * 64 * sizeof(float), stream);
    hipMemsetAsync(agg2, 0, (size_t)N_NODES * 32 * sizeof(float), stream);
    hipMemsetAsync(cntv, 0, (size_t)N_NODES * sizeof(float), stream);

    // Layer 1: project (128 -> 64+64), scatter-mean, finalize+relu
    gemm_dual<128, 64, 32, 64><<<(N_NODES + 31) / 32, 256, 0, stream>>>(x, w1l, w1r, xl, xr);
    scatter_add<64, true><<<(N_EDGES * 16 + 255) / 256, 256, 0, stream>>>(xl, ei, agg1, cntv);
    finalize_k<64, true><<<(N_NODES * 16 + 255) / 256, 256, 0, stream>>>(agg1, cntv, b1l, xr, h);

    // Layer 2: project (64 -> 32+32), scatter-mean, finalize
    gemm_dual<64, 32, 16, 64><<<(N_NODES + 63) / 64, 256, 0, stream>>>(h, w2l, w2r, hl, hr);
    scatter_add<32, false><<<(N_EDGES * 8 + 255) / 256, 256, 0, stream>>>(hl, ei, agg2, nullptr);
    finalize_k<32, false><<<(N_NODES * 8 + 255) / 256, 256, 0, stream>>>(agg2, cntv, b2l, hr, out);
}

// Round 2
// 278.191 us; speedup vs baseline: 3.5126x; 3.5126x over previous
//
#include <hip/hip_runtime.h>

#define N_NODES 100000
#define N_EDGES 600000
#define N_PAD   100352      // N_NODES rounded up to 1024 (scan tiles)
#define NB1     98          // ceil(N_NODES/1024)

// ---------------------------------------------------------------------------
// Fused dual GEMM: outl = x @ wl^T, outr = x @ wr^T   (wl, wr are [F][K])
// ---------------------------------------------------------------------------
template<int K, int F, int OG, int KT>
__global__ __launch_bounds__(256) void gemm_dual(
    const float* __restrict__ x,
    const float* __restrict__ wl,
    const float* __restrict__ wr,
    float* __restrict__ outl,
    float* __restrict__ outr)
{
    constexpr int TWOF = 2 * F;
    constexpr int NO   = TWOF / OG;   // outputs per thread
    constexpr int NG   = 256 / OG;    // node groups per block
    constexpr int NN   = 4;           // nodes per thread
    constexpr int NPB  = NG * NN;     // nodes per block
    constexpr int WS   = KT + 4;      // padded W row stride
    constexpr int NKT  = K / KT;

    __shared__ float Wlds[TWOF * WS];
    __shared__ float xs[NPB * K];

    const int tid = threadIdx.x;
    const int n0  = blockIdx.x * NPB;

    for (int i = tid; i < NPB * K; i += 256) {
        int nr = i / K;
        int k  = i - nr * K;
        int node = n0 + nr;
        xs[i] = (node < N_NODES) ? x[node * K + k] : 0.0f;
    }

    const int og = tid % OG;
    const int ng = tid / OG;

    float acc[NN][NO];
    #pragma unroll
    for (int j = 0; j < NN; ++j)
        #pragma unroll
        for (int i = 0; i < NO; ++i) acc[j][i] = 0.0f;

    for (int kt = 0; kt < NKT; ++kt) {
        const int k0 = kt * KT;
        __syncthreads();
        for (int i = tid; i < TWOF * KT; i += 256) {
            int o  = i / KT;
            int kk = i - o * KT;
            float v = (o < F) ? wl[o * K + k0 + kk] : wr[(o - F) * K + k0 + kk];
            Wlds[o * WS + kk] = v;
        }
        __syncthreads();

        #pragma unroll
        for (int k4 = 0; k4 < KT / 4; ++k4) {
            float4 wv[NO];
            #pragma unroll
            for (int i = 0; i < NO; ++i)
                wv[i] = *(const float4*)&Wlds[(og + OG * i) * WS + 4 * k4];
            float4 xv[NN];
            #pragma unroll
            for (int j = 0; j < NN; ++j)
                xv[j] = *(const float4*)&xs[(ng * NN + j) * K + k0 + 4 * k4];
            #pragma unroll
            for (int j = 0; j < NN; ++j) {
                #pragma unroll
                for (int i = 0; i < NO; ++i) {
                    acc[j][i] += xv[j].x * wv[i].x;
                    acc[j][i] += xv[j].y * wv[i].y;
                    acc[j][i] += xv[j].z * wv[i].z;
                    acc[j][i] += xv[j].w * wv[i].w;
                }
            }
        }
    }

    #pragma unroll
    for (int j = 0; j < NN; ++j) {
        int node = n0 + ng * NN + j;
        if (node >= N_NODES) continue;
        #pragma unroll
        for (int i = 0; i < NO; ++i) {
            int o = og + OG * i;
            if (o < F) outl[node * F + o] = acc[j][i];
            else       outr[node * F + (o - F)] = acc[j][i];
        }
    }
}

// ---------------------------------------------------------------------------
// CSR build: degree histogram -> 3-kernel exclusive scan -> edge bucketing
// ---------------------------------------------------------------------------
__global__ __launch_bounds__(256) void hist_deg(const int* __restrict__ ei,
                                                int* __restrict__ deg)
{
    int e = blockIdx.x * 256 + threadIdx.x;
    if (e < N_EDGES) atomicAdd(&deg[ei[N_EDGES + e]], 1);
}

// per-block inclusive scan over 1024 ints; tmp = in-block inclusive, bs[b] = block sum
__global__ __launch_bounds__(256) void scan_blocks(const int* __restrict__ deg,
                                                   int* __restrict__ tmp,
                                                   int* __restrict__ bs)
{
    __shared__ int s[256];
    int b = blockIdx.x, tid = threadIdx.x;
    int i = b * 1024 + tid * 4;
    int4 v = *(const int4*)&deg[i];          // deg padded to N_PAD, zeros beyond N
    int p0 = v.x, p1 = p0 + v.y, p2 = p1 + v.z, p3 = p2 + v.w;
    s[tid] = p3;
    __syncthreads();
    for (int off = 1; off < 256; off <<= 1) {
        int t = (tid >= off) ? s[tid - off] : 0;
        __syncthreads();
        s[tid] += t;
        __syncthreads();
    }
    int excl = s[tid] - p3;
    int4 o; o.x = excl + p0; o.y = excl + p1; o.z = excl + p2; o.w = excl + p3;
    *(int4*)&tmp[i] = o;
    if (tid == 255) bs[b] = s[255];
}

__global__ __launch_bounds__(128) void scan_sums(int* __restrict__ bs,
                                                 int* __restrict__ boff)
{
    __shared__ int s[128];
    int tid = threadIdx.x;
    s[tid] = (tid < NB1) ? bs[tid] : 0;
    __syncthreads();
    for (int off = 1; off < 128; off <<= 1) {
        int t = (tid >= off) ? s[tid - off] : 0;
        __syncthreads();
        s[tid] += t;
        __syncthreads();
    }
    if (tid < NB1) boff[tid] = s[tid];
}

// row_ptr[i+1] = tmp[i] + boff[b-1]; cursor[i] = row_ptr[i+1] - deg[i]
__global__ __launch_bounds__(256) void scan_add(const int* __restrict__ tmp,
                                                const int* __restrict__ deg,
                                                const int* __restrict__ boff,
                                                int* __restrict__ row_ptr,
                                                int* __restrict__ cursor)
{
    int b = blockIdx.x, tid = threadIdx.x;
    int i = b * 1024 + tid * 4;
    int off = (b > 0) ? boff[b - 1] : 0;
    int4 t = *(const int4*)&tmp[i];
    int4 d = *(const int4*)&deg[i];
    if (b == 0 && tid == 0) row_ptr[0] = 0;
    if (i + 0 < N_NODES) { row_ptr[i + 1] = t.x + off; cursor[i + 0] = t.x + off - d.x; }
    if (i + 1 < N_NODES) { row_ptr[i + 2] = t.y + off; cursor[i + 1] = t.y + off - d.y; }
    if (i + 2 < N_NODES) { row_ptr[i + 3] = t.z + off; cursor[i + 2] = t.z + off - d.z; }
    if (i + 3 < N_NODES) { row_ptr[i + 4] = t.w + off; cursor[i + 3] = t.w + off - d.w; }
}

__global__ __launch_bounds__(256) void build_csr(const int* __restrict__ ei,
                                                 int* __restrict__ cursor,
                                                 int* __restrict__ csr_src)
{
    int e = blockIdx.x * 256 + threadIdx.x;
    if (e >= N_EDGES) return;
    int d = ei[N_EDGES + e];
    int pos = atomicAdd(&cursor[d], 1);
    csr_src[pos] = ei[e];
}

// ---------------------------------------------------------------------------
// Gather-aggregate + fused epilogue:
// out[n] = [relu]( (sum_{s in csr[n]} feat[s]) / max(deg,1) + bias + right[n] )
// out may alias right (per-thread read-before-write), must NOT alias feat.
// ---------------------------------------------------------------------------
template<int F, bool RELU>
__global__ __launch_bounds__(256) void gather_agg(
    const float* __restrict__ feat,
    const int* __restrict__ row_ptr,
    const int* __restrict__ csr_src,
    const float* __restrict__ bias,
    const float* __restrict__ right,
    float* __restrict__ out)
{
    constexpr int F4 = F / 4;
    int t = blockIdx.x * 256 + threadIdx.x;
    int n = t / F4;
    int q = t - n * F4;
    if (n >= N_NODES) return;
    int beg = row_ptr[n], end = row_ptr[n + 1];
    float4 acc = make_float4(0.f, 0.f, 0.f, 0.f);
    for (int i = beg; i < end; ++i) {
        int s = csr_src[i];
        float4 v = *(const float4*)&feat[s * F + 4 * q];
        acc.x += v.x; acc.y += v.y; acc.z += v.z; acc.w += v.w;
    }
    float inv = 1.0f / (float)max(end - beg, 1);
    float4 r = *(const float4*)&right[n * F + 4 * q];
    float4 bv = *(const float4*)&bias[4 * q];
    float4 o;
    o.x = fmaf(acc.x, inv, bv.x) + r.x;
    o.y = fmaf(acc.y, inv, bv.y) + r.y;
    o.z = fmaf(acc.z, inv, bv.z) + r.z;
    o.w = fmaf(acc.w, inv, bv.w) + r.w;
    if (RELU) {
        o.x = fmaxf(o.x, 0.f); o.y = fmaxf(o.y, 0.f);
        o.z = fmaxf(o.z, 0.f); o.w = fmaxf(o.w, 0.f);
    }
    *(float4*)&out[n * F + 4 * q] = o;
}

extern "C" void kernel_launch(void* const* d_in, const int* in_sizes, int n_in,
                              void* d_out, int out_size, void* d_ws, size_t ws_size,
                              hipStream_t stream)
{
    const float* x   = (const float*)d_in[0];
    const int*   ei  = (const int*)d_in[1];   // int32 (JAX x64 disabled)
    const float* w1l = (const float*)d_in[2];
    const float* b1l = (const float*)d_in[3];
    const float* w1r = (const float*)d_in[4];
    const float* w2l = (const float*)d_in[5];
    const float* b2l = (const float*)d_in[6];
    const float* w2r = (const float*)d_in[7];
    float* out = (float*)d_out;

    char* ws = (char*)d_ws;
    // layout (16B aligned):
    //   [0, 25.6M)        xl  (100000x64 f32)  -> later hl (12.8M) + hr (12.8M)
    //   [25.6M, 51.2M)    xr  (100000x64 f32)  -> h written in place by gather1
    //   [51.2M, 53.6M)    csr_src (600000 i32)
    //   [53.6M, +)        deg[N_PAD], tmp[N_PAD], row_ptr[N+1], cursor[N], bs[NB1], boff[NB1]
    float* xl      = (float*)(ws + 0);
    float* xr      = (float*)(ws + 25600000);
    int*   csr_src = (int*)  (ws + 51200000);
    int*   deg     = (int*)  (ws + 53600000);
    int*   tmp     = (int*)  (ws + 53600000 + 401408);            // N_PAD*4
    int*   row_ptr = (int*)  (ws + 53600000 + 2 * 401408);
    int*   cursor  = (int*)  (ws + 53600000 + 2 * 401408 + 400016);
    int*   bs      = (int*)  (ws + 53600000 + 2 * 401408 + 400016 + 400000);
    int*   boff    = (int*)  (ws + 53600000 + 2 * 401408 + 400016 + 400000 + 512);
    float* h  = xr;                      // in-place (right/out alias is safe)
    float* hl = xl;
    float* hr = (float*)(ws + 12800000);

    // ---- CSR build (edge_index is the only input to this) ----
    hipMemsetAsync(deg, 0, N_PAD * sizeof(int), stream);
    hist_deg<<<(N_EDGES + 255) / 256, 256, 0, stream>>>(ei, deg);
    scan_blocks<<<NB1, 256, 0, stream>>>(deg, tmp, bs);
    scan_sums<<<1, 128, 0, stream>>>(bs, boff);
    scan_add<<<NB1, 256, 0, stream>>>(tmp, deg, boff, row_ptr, cursor);
    build_csr<<<(N_EDGES + 255) / 256, 256, 0, stream>>>(ei, cursor, csr_src);

    // ---- Layer 1: project (128 -> 64||64), gather-mean + relu ----
    gemm_dual<128, 64, 32, 64><<<(N_NODES + 31) / 32, 256, 0, stream>>>(x, w1l, w1r, xl, xr);
    gather_agg<64, true><<<(N_NODES * 16 + 255) / 256, 256, 0, stream>>>(
        xl, row_ptr, csr_src, b1l, xr, h);

    // ---- Layer 2: project (64 -> 32||32), gather-mean ----
    gemm_dual<64, 32, 16, 64><<<(N_NODES + 63) / 64, 256, 0, stream>>>(h, w2l, w2r, hl, hr);
    gather_agg<32, false><<<(N_NODES * 8 + 255) / 256, 256, 0, stream>>>(
        hl, row_ptr, csr_src, b2l, hr, out);
}

// Round 3
// 166.927 us; speedup vs baseline: 5.8540x; 1.6665x over previous
//
#include <hip/hip_runtime.h>

#define N_NODES 100000
#define N_EDGES 600000
#define N_PAD   100352      // N_NODES rounded up to 1024 (scan tiles)
#define NB1     98          // ceil(N_NODES/1024)

typedef __bf16 bf16x8 __attribute__((ext_vector_type(8)));
typedef float  f32x4  __attribute__((ext_vector_type(4)));
typedef unsigned short u16x8 __attribute__((ext_vector_type(8)));
typedef unsigned short u16x4 __attribute__((ext_vector_type(4)));

__device__ inline unsigned short f2bf(float f) {
    __bf16 h = (__bf16)f;                 // RNE via v_cvt
    return __builtin_bit_cast(unsigned short, h);
}

// read one 16x16x32 A/B fragment from swizzled bf16 LDS
// row-major [rows][K] bf16, byte = (row*KB + kbyte) ^ ((row&7)<<4)
__device__ inline bf16x8 read_frag(const unsigned short* lds, int row, int kbyte, int KB) {
    int byte = (row * KB + kbyte) ^ ((row & 7) << 4);
    u16x8 v = *(const u16x8*)((const char*)lds + byte);
    return __builtin_bit_cast(bf16x8, v);
}

// ---------------------------------------------------------------------------
// MFMA dual GEMM: outl = x @ wl^T, outr = x @ wr^T  (wl, wr are [F][K] f32)
// BM=128 rows/block, 256 threads = 4 waves; wave w owns rows [w*32, w*32+32).
// x-tile and combined W ([2F][K]) staged in LDS as bf16 with XOR swizzle.
// ---------------------------------------------------------------------------
template<int K, int F>
__global__ __launch_bounds__(256) void gemm_mfma(
    const float* __restrict__ x,
    const float* __restrict__ wl,
    const float* __restrict__ wr,
    float* __restrict__ outl,
    float* __restrict__ outr)
{
    constexpr int N2  = 2 * F;
    constexpr int BM  = 128;
    constexpr int KB  = 2 * K;      // LDS row bytes (bf16)
    constexpr int NKT = K / 32;     // K-steps of 32
    constexpr int NT  = N2 / 16;    // n-tiles
    constexpr int K4  = K / 4;      // float4s per row

    __shared__ unsigned short XS[BM * K];
    __shared__ unsigned short WS[N2 * K];

    const int tid = threadIdx.x;
    const int n0  = blockIdx.x * BM;

    // stage x-tile (f32 -> bf16, swizzled)
    for (int idx = tid; idx < BM * K4; idx += 256) {
        int row = idx / K4, c4 = idx - row * K4;
        int node = n0 + row;
        float4 v = (node < N_NODES) ? *(const float4*)&x[node * K + 4 * c4]
                                    : make_float4(0.f, 0.f, 0.f, 0.f);
        u16x4 o = { f2bf(v.x), f2bf(v.y), f2bf(v.z), f2bf(v.w) };
        int byte = (row * KB + 8 * c4) ^ ((row & 7) << 4);
        *(u16x4*)((char*)XS + byte) = o;
    }
    // stage W: rows 0..F-1 from wl, F..2F-1 from wr
    for (int idx = tid; idx < N2 * K4; idx += 256) {
        int row = idx / K4, c4 = idx - row * K4;
        const float* src = (row < F) ? &wl[row * K] : &wr[(row - F) * K];
        float4 v = *(const float4*)&src[4 * c4];
        u16x4 o = { f2bf(v.x), f2bf(v.y), f2bf(v.z), f2bf(v.w) };
        int byte = (row * KB + 8 * c4) ^ ((row & 7) << 4);
        *(u16x4*)((char*)WS + byte) = o;
    }
    __syncthreads();

    const int w    = tid >> 6;      // wave 0..3
    const int l    = tid & 63;
    const int lrow = l & 15;
    const int khalf = (l >> 4) * 16;  // byte offset of this lane's 8-k chunk within 32-k step

    f32x4 acc[2][NT];
    #pragma unroll
    for (int mt = 0; mt < 2; ++mt)
        #pragma unroll
        for (int nt = 0; nt < NT; ++nt) acc[mt][nt] = (f32x4){0.f, 0.f, 0.f, 0.f};

    #pragma unroll
    for (int kt = 0; kt < NKT; ++kt) {
        int kb = kt * 64 + khalf;
        bf16x8 a0 = read_frag(XS, w * 32 + lrow,      kb, KB);
        bf16x8 a1 = read_frag(XS, w * 32 + 16 + lrow, kb, KB);
        #pragma unroll
        for (int nt = 0; nt < NT; ++nt) {
            bf16x8 b = read_frag(WS, nt * 16 + lrow, kb, KB);
            acc[0][nt] = __builtin_amdgcn_mfma_f32_16x16x32_bf16(a0, b, acc[0][nt], 0, 0, 0);
            acc[1][nt] = __builtin_amdgcn_mfma_f32_16x16x32_bf16(a1, b, acc[1][nt], 0, 0, 0);
        }
    }

    // epilogue: D col = lane&15, row = (lane>>4)*4 + reg
    const int orow = (l >> 4) * 4;
    #pragma unroll
    for (int mt = 0; mt < 2; ++mt) {
        #pragma unroll
        for (int r = 0; r < 4; ++r) {
            int node = n0 + w * 32 + mt * 16 + orow + r;
            if (node >= N_NODES) continue;
            #pragma unroll
            for (int nt = 0; nt < NT; ++nt) {
                int col = nt * 16 + lrow;
                float val = acc[mt][nt][r];
                if (col < F) outl[node * F + col] = val;
                else         outr[node * F + (col - F)] = val;
            }
        }
    }
}

// ---------------------------------------------------------------------------
// CSR build: degree histogram -> 3-kernel exclusive scan -> edge bucketing
// ---------------------------------------------------------------------------
__global__ __launch_bounds__(256) void hist_deg(const int* __restrict__ ei,
                                                int* __restrict__ deg)
{
    int e = blockIdx.x * 256 + threadIdx.x;
    if (e < N_EDGES) atomicAdd(&deg[ei[N_EDGES + e]], 1);
}

__global__ __launch_bounds__(256) void scan_blocks(const int* __restrict__ deg,
                                                   int* __restrict__ tmp,
                                                   int* __restrict__ bs)
{
    __shared__ int s[256];
    int b = blockIdx.x, tid = threadIdx.x;
    int i = b * 1024 + tid * 4;
    int4 v = *(const int4*)&deg[i];
    int p0 = v.x, p1 = p0 + v.y, p2 = p1 + v.z, p3 = p2 + v.w;
    s[tid] = p3;
    __syncthreads();
    for (int off = 1; off < 256; off <<= 1) {
        int t = (tid >= off) ? s[tid - off] : 0;
        __syncthreads();
        s[tid] += t;
        __syncthreads();
    }
    int excl = s[tid] - p3;
    int4 o; o.x = excl + p0; o.y = excl + p1; o.z = excl + p2; o.w = excl + p3;
    *(int4*)&tmp[i] = o;
    if (tid == 255) bs[b] = s[255];
}

__global__ __launch_bounds__(128) void scan_sums(int* __restrict__ bs,
                                                 int* __restrict__ boff)
{
    __shared__ int s[128];
    int tid = threadIdx.x;
    s[tid] = (tid < NB1) ? bs[tid] : 0;
    __syncthreads();
    for (int off = 1; off < 128; off <<= 1) {
        int t = (tid >= off) ? s[tid - off] : 0;
        __syncthreads();
        s[tid] += t;
        __syncthreads();
    }
    if (tid < NB1) boff[tid] = s[tid];
}

__global__ __launch_bounds__(256) void scan_add(const int* __restrict__ tmp,
                                                const int* __restrict__ deg,
                                                const int* __restrict__ boff,
                                                int* __restrict__ row_ptr,
                                                int* __restrict__ cursor)
{
    int b = blockIdx.x, tid = threadIdx.x;
    int i = b * 1024 + tid * 4;
    int off = (b > 0) ? boff[b - 1] : 0;
    int4 t = *(const int4*)&tmp[i];
    int4 d = *(const int4*)&deg[i];
    if (b == 0 && tid == 0) row_ptr[0] = 0;
    if (i + 0 < N_NODES) { row_ptr[i + 1] = t.x + off; cursor[i + 0] = t.x + off - d.x; }
    if (i + 1 < N_NODES) { row_ptr[i + 2] = t.y + off; cursor[i + 1] = t.y + off - d.y; }
    if (i + 2 < N_NODES) { row_ptr[i + 3] = t.z + off; cursor[i + 2] = t.z + off - d.z; }
    if (i + 3 < N_NODES) { row_ptr[i + 4] = t.w + off; cursor[i + 3] = t.w + off - d.w; }
}

__global__ __launch_bounds__(256) void build_csr(const int* __restrict__ ei,
                                                 int* __restrict__ cursor,
                                                 int* __restrict__ csr_src)
{
    int e = blockIdx.x * 256 + threadIdx.x;
    if (e >= N_EDGES) return;
    int d = ei[N_EDGES + e];
    int pos = atomicAdd(&cursor[d], 1);
    csr_src[pos] = ei[e];
}

// ---------------------------------------------------------------------------
// Gather-aggregate + fused epilogue:
// out[n] = [relu]( (sum_{s in csr[n]} feat[s]) / max(deg,1) + bias + right[n] )
// ---------------------------------------------------------------------------
template<int F, bool RELU>
__global__ __launch_bounds__(256) void gather_agg(
    const float* __restrict__ feat,
    const int* __restrict__ row_ptr,
    const int* __restrict__ csr_src,
    const float* __restrict__ bias,
    const float* __restrict__ right,
    float* __restrict__ out)
{
    constexpr int F4 = F / 4;
    int t = blockIdx.x * 256 + threadIdx.x;
    int n = t / F4;
    int q = t - n * F4;
    if (n >= N_NODES) return;
    int beg = row_ptr[n], end = row_ptr[n + 1];
    float4 acc = make_float4(0.f, 0.f, 0.f, 0.f);
    for (int i = beg; i < end; ++i) {
        int s = csr_src[i];
        float4 v = *(const float4*)&feat[s * F + 4 * q];
        acc.x += v.x; acc.y += v.y; acc.z += v.z; acc.w += v.w;
    }
    float inv = 1.0f / (float)max(end - beg, 1);
    float4 r = *(const float4*)&right[n * F + 4 * q];
    float4 bv = *(const float4*)&bias[4 * q];
    float4 o;
    o.x = fmaf(acc.x, inv, bv.x) + r.x;
    o.y = fmaf(acc.y, inv, bv.y) + r.y;
    o.z = fmaf(acc.z, inv, bv.z) + r.z;
    o.w = fmaf(acc.w, inv, bv.w) + r.w;
    if (RELU) {
        o.x = fmaxf(o.x, 0.f); o.y = fmaxf(o.y, 0.f);
        o.z = fmaxf(o.z, 0.f); o.w = fmaxf(o.w, 0.f);
    }
    *(float4*)&out[n * F + 4 * q] = o;
}

extern "C" void kernel_launch(void* const* d_in, const int* in_sizes, int n_in,
                              void* d_out, int out_size, void* d_ws, size_t ws_size,
                              hipStream_t stream)
{
    const float* x   = (const float*)d_in[0];
    const int*   ei  = (const int*)d_in[1];   // int32 (JAX x64 disabled)
    const float* w1l = (const float*)d_in[2];
    const float* b1l = (const float*)d_in[3];
    const float* w1r = (const float*)d_in[4];
    const float* w2l = (const float*)d_in[5];
    const float* b2l = (const float*)d_in[6];
    const float* w2r = (const float*)d_in[7];
    float* out = (float*)d_out;

    char* ws = (char*)d_ws;
    float* xl      = (float*)(ws + 0);
    float* xr      = (float*)(ws + 25600000);
    int*   csr_src = (int*)  (ws + 51200000);
    int*   deg     = (int*)  (ws + 53600000);
    int*   tmp     = (int*)  (ws + 53600000 + 401408);
    int*   row_ptr = (int*)  (ws + 53600000 + 2 * 401408);
    int*   cursor  = (int*)  (ws + 53600000 + 2 * 401408 + 400016);
    int*   bs      = (int*)  (ws + 53600000 + 2 * 401408 + 400016 + 400000);
    int*   boff    = (int*)  (ws + 53600000 + 2 * 401408 + 400016 + 400000 + 512);
    float* h  = xr;                      // gather1 writes h in place of xr
    float* hl = xl;
    float* hr = (float*)(ws + 12800000);

    // ---- CSR build ----
    hipMemsetAsync(deg, 0, N_PAD * sizeof(int), stream);
    hist_deg<<<(N_EDGES + 255) / 256, 256, 0, stream>>>(ei, deg);
    scan_blocks<<<NB1, 256, 0, stream>>>(deg, tmp, bs);
    scan_sums<<<1, 128, 0, stream>>>(bs, boff);
    scan_add<<<NB1, 256, 0, stream>>>(tmp, deg, boff, row_ptr, cursor);
    build_csr<<<(N_EDGES + 255) / 256, 256, 0, stream>>>(ei, cursor, csr_src);

    // ---- Layer 1: MFMA project (128 -> 64||64), gather-mean + relu ----
    gemm_mfma<128, 64><<<(N_NODES + 127) / 128, 256, 0, stream>>>(x, w1l, w1r, xl, xr);
    gather_agg<64, true><<<(N_NODES * 16 + 255) / 256, 256, 0, stream>>>(
        xl, row_ptr, csr_src, b1l, xr, h);

    // ---- Layer 2: MFMA project (64 -> 32||32), gather-mean ----
    gemm_mfma<64, 32><<<(N_NODES + 127) / 128, 256, 0, stream>>>(h, w2l, w2r, hl, hr);
    gather_agg<32, false><<<(N_NODES * 8 + 255) / 256, 256, 0, stream>>>(
        hl, row_ptr, csr_src, b2l, hr, out);
}

// Round 4
// 164.093 us; speedup vs baseline: 5.9551x; 1.0173x over previous
//
#include <hip/hip_runtime.h>

#define N_NODES 100000
#define N_EDGES 600000
#define N_PAD   100352      // N_NODES rounded up to 1024 (scan tiles)
#define NB1     98          // ceil(N_NODES/1024)

typedef __bf16 bf16x8 __attribute__((ext_vector_type(8)));
typedef float  f32x4  __attribute__((ext_vector_type(4)));
typedef unsigned short u16x8 __attribute__((ext_vector_type(8)));

__device__ inline unsigned short f2bf(float f) {
    __bf16 h = (__bf16)f;                 // RNE via v_cvt
    return __builtin_bit_cast(unsigned short, h);
}
__device__ inline float bf2f(unsigned short u) {
    return __builtin_bit_cast(float, ((unsigned)u) << 16);
}

// load 8 consecutive f32, convert to a bf16x8 fragment (zero if !valid)
__device__ inline bf16x8 ldfrag_f32(const float* p, bool valid) {
    float4 u = valid ? *(const float4*)p       : make_float4(0.f,0.f,0.f,0.f);
    float4 w = valid ? *(const float4*)(p + 4) : make_float4(0.f,0.f,0.f,0.f);
    u16x8 o;
    o[0]=f2bf(u.x); o[1]=f2bf(u.y); o[2]=f2bf(u.z); o[3]=f2bf(u.w);
    o[4]=f2bf(w.x); o[5]=f2bf(w.y); o[6]=f2bf(w.z); o[7]=f2bf(w.w);
    return __builtin_bit_cast(bf16x8, o);
}
__device__ inline bf16x8 ldfrag_bf16(const unsigned short* p, bool valid) {
    u16x8 v = valid ? *(const u16x8*)p : (u16x8){0,0,0,0,0,0,0,0};
    return __builtin_bit_cast(bf16x8, v);
}

// ---------------------------------------------------------------------------
// LDS-free MFMA dual GEMM: outl = x @ wl^T, outr = x @ wr^T (bf16 outputs).
// One wave per 32 rows, fully independent (no barriers, no LDS).
// A-frags straight from global (f32 or bf16), B-frags from L2-resident W.
// ---------------------------------------------------------------------------
template<int K, int F, bool A_BF16>
__global__ __launch_bounds__(256) void gemm_direct(
    const void* __restrict__ xv,
    const float* __restrict__ wl,
    const float* __restrict__ wr,
    unsigned short* __restrict__ outl,
    unsigned short* __restrict__ outr)
{
    constexpr int N2  = 2 * F;
    constexpr int NT  = N2 / 16;   // n-tiles
    constexpr int NKT = K / 32;    // k-steps

    const int tid  = threadIdx.x;
    const int wid  = (blockIdx.x * 256 + tid) >> 6;
    const int l    = tid & 63;
    const int base = wid * 32;
    if (base >= N_NODES) return;

    const int lrow = l & 15;
    const int ksub = (l >> 4) * 8;          // element offset within 32-k step
    const int r0 = base + lrow;
    const int r1 = base + 16 + lrow;
    const bool v0 = r0 < N_NODES;
    const bool v1 = r1 < N_NODES;

    const float*          xf  = (const float*)xv;
    const unsigned short* x16 = (const unsigned short*)xv;

    f32x4 acc[2][NT];
    #pragma unroll
    for (int mt = 0; mt < 2; ++mt)
        #pragma unroll
        for (int nt = 0; nt < NT; ++nt) acc[mt][nt] = (f32x4){0.f,0.f,0.f,0.f};

    #pragma unroll 1
    for (int kt = 0; kt < NKT; ++kt) {
        const int kc = kt * 32 + ksub;
        bf16x8 a0 = A_BF16 ? ldfrag_bf16(x16 + r0 * K + kc, v0)
                           : ldfrag_f32 (xf  + r0 * K + kc, v0);
        bf16x8 a1 = A_BF16 ? ldfrag_bf16(x16 + r1 * K + kc, v1)
                           : ldfrag_f32 (xf  + r1 * K + kc, v1);
        #pragma unroll
        for (int nt = 0; nt < NT; ++nt) {
            int wrow = nt * 16 + lrow;
            const float* wp = (wrow < F) ? &wl[wrow * K + kc] : &wr[(wrow - F) * K + kc];
            bf16x8 b = ldfrag_f32(wp, true);
            acc[0][nt] = __builtin_amdgcn_mfma_f32_16x16x32_bf16(a0, b, acc[0][nt], 0, 0, 0);
            acc[1][nt] = __builtin_amdgcn_mfma_f32_16x16x32_bf16(a1, b, acc[1][nt], 0, 0, 0);
        }
    }

    // D: col = lane&15, row = (lane>>4)*4 + reg
    const int orow = (l >> 4) * 4;
    #pragma unroll
    for (int mt = 0; mt < 2; ++mt) {
        #pragma unroll
        for (int r = 0; r < 4; ++r) {
            int node = base + mt * 16 + orow + r;
            if (node >= N_NODES) continue;
            #pragma unroll
            for (int nt = 0; nt < NT; ++nt) {
                int col = nt * 16 + lrow;
                unsigned short hv = f2bf(acc[mt][nt][r]);
                if (col < F) outl[node * F + col] = hv;
                else         outr[node * F + (col - F)] = hv;
            }
        }
    }
}

// ---------------------------------------------------------------------------
// CSR build: degree histogram -> scan -> edge bucketing
// ---------------------------------------------------------------------------
__global__ __launch_bounds__(256) void hist_deg(const int* __restrict__ ei,
                                                int* __restrict__ deg)
{
    int e = blockIdx.x * 256 + threadIdx.x;
    if (e < N_EDGES) atomicAdd(&deg[ei[N_EDGES + e]], 1);
}

__global__ __launch_bounds__(256) void scan_blocks(const int* __restrict__ deg,
                                                   int* __restrict__ tmp,
                                                   int* __restrict__ bs)
{
    __shared__ int s[256];
    int b = blockIdx.x, tid = threadIdx.x;
    int i = b * 1024 + tid * 4;
    int4 v = *(const int4*)&deg[i];
    int p0 = v.x, p1 = p0 + v.y, p2 = p1 + v.z, p3 = p2 + v.w;
    s[tid] = p3;
    __syncthreads();
    for (int off = 1; off < 256; off <<= 1) {
        int t = (tid >= off) ? s[tid - off] : 0;
        __syncthreads();
        s[tid] += t;
        __syncthreads();
    }
    int excl = s[tid] - p3;
    int4 o; o.x = excl + p0; o.y = excl + p1; o.z = excl + p2; o.w = excl + p3;
    *(int4*)&tmp[i] = o;
    if (tid == 255) bs[b] = s[255];
}

__global__ __launch_bounds__(128) void scan_sums(int* __restrict__ bs,
                                                 int* __restrict__ boff)
{
    __shared__ int s[128];
    int tid = threadIdx.x;
    s[tid] = (tid < NB1) ? bs[tid] : 0;
    __syncthreads();
    for (int off = 1; off < 128; off <<= 1) {
        int t = (tid >= off) ? s[tid - off] : 0;
        __syncthreads();
        s[tid] += t;
        __syncthreads();
    }
    if (tid < NB1) boff[tid] = s[tid];
}

__global__ __launch_bounds__(256) void scan_add(const int* __restrict__ tmp,
                                                const int* __restrict__ deg,
                                                const int* __restrict__ boff,
                                                int* __restrict__ row_ptr,
                                                int* __restrict__ cursor)
{
    int b = blockIdx.x, tid = threadIdx.x;
    int i = b * 1024 + tid * 4;
    int off = (b > 0) ? boff[b - 1] : 0;
    int4 t = *(const int4*)&tmp[i];
    int4 d = *(const int4*)&deg[i];
    if (b == 0 && tid == 0) row_ptr[0] = 0;
    if (i + 0 < N_NODES) { row_ptr[i + 1] = t.x + off; cursor[i + 0] = t.x + off - d.x; }
    if (i + 1 < N_NODES) { row_ptr[i + 2] = t.y + off; cursor[i + 1] = t.y + off - d.y; }
    if (i + 2 < N_NODES) { row_ptr[i + 3] = t.z + off; cursor[i + 2] = t.z + off - d.z; }
    if (i + 3 < N_NODES) { row_ptr[i + 4] = t.w + off; cursor[i + 3] = t.w + off - d.w; }
}

__global__ __launch_bounds__(256) void build_csr(const int* __restrict__ ei,
                                                 int* __restrict__ cursor,
                                                 int* __restrict__ csr_src)
{
    int e = blockIdx.x * 256 + threadIdx.x;
    if (e >= N_EDGES) return;
    int d = ei[N_EDGES + e];
    int pos = atomicAdd(&cursor[d], 1);
    csr_src[pos] = ei[e];
}

// ---------------------------------------------------------------------------
// Gather-aggregate + fused epilogue (bf16 feat/right, bf16 or f32 out):
// out[n] = [relu]( (sum_{s in csr[n]} feat[s]) / max(deg,1) + bias + right[n] )
// ---------------------------------------------------------------------------
template<int F, bool RELU, bool OUT_BF16>
__global__ __launch_bounds__(256) void gather_agg(
    const unsigned short* __restrict__ feat,
    const int* __restrict__ row_ptr,
    const int* __restrict__ csr_src,
    const float* __restrict__ bias,
    const unsigned short* __restrict__ right,
    void* __restrict__ outv)
{
    constexpr int C8 = F / 8;
    int t = blockIdx.x * 256 + threadIdx.x;
    int n = t / C8;
    int q = t - n * C8;
    if (n >= N_NODES) return;
    int beg = row_ptr[n], end = row_ptr[n + 1];

    float acc[8] = {0.f,0.f,0.f,0.f,0.f,0.f,0.f,0.f};
    for (int i = beg; i < end; ++i) {
        int s = csr_src[i];
        u16x8 v = *(const u16x8*)&feat[s * F + 8 * q];
        #pragma unroll
        for (int j = 0; j < 8; ++j) acc[j] += bf2f(v[j]);
    }
    float inv = 1.0f / (float)max(end - beg, 1);
    u16x8 rv = *(const u16x8*)&right[n * F + 8 * q];
    float4 b0 = *(const float4*)&bias[8 * q];
    float4 b1 = *(const float4*)&bias[8 * q + 4];
    float bb[8] = {b0.x,b0.y,b0.z,b0.w,b1.x,b1.y,b1.z,b1.w};

    float o[8];
    #pragma unroll
    for (int j = 0; j < 8; ++j) {
        o[j] = fmaf(acc[j], inv, bb[j]) + bf2f(rv[j]);
        if (RELU) o[j] = fmaxf(o[j], 0.f);
    }
    if (OUT_BF16) {
        u16x8 ov;
        #pragma unroll
        for (int j = 0; j < 8; ++j) ov[j] = f2bf(o[j]);
        *(u16x8*)((unsigned short*)outv + n * F + 8 * q) = ov;
    } else {
        float* op = (float*)outv + n * F + 8 * q;
        *(float4*)op       = make_float4(o[0], o[1], o[2], o[3]);
        *(float4*)(op + 4) = make_float4(o[4], o[5], o[6], o[7]);
    }
}

extern "C" void kernel_launch(void* const* d_in, const int* in_sizes, int n_in,
                              void* d_out, int out_size, void* d_ws, size_t ws_size,
                              hipStream_t stream)
{
    const float* x   = (const float*)d_in[0];
    const int*   ei  = (const int*)d_in[1];   // int32 (JAX x64 disabled)
    const float* w1l = (const float*)d_in[2];
    const float* b1l = (const float*)d_in[3];
    const float* w1r = (const float*)d_in[4];
    const float* w2l = (const float*)d_in[5];
    const float* b2l = (const float*)d_in[6];
    const float* w2r = (const float*)d_in[7];
    float* out = (float*)d_out;

    char* ws = (char*)d_ws;
    // bf16 intermediates:
    unsigned short* xl = (unsigned short*)(ws + 0);          // 100000x64 bf16, 12.8MB
    unsigned short* xr = (unsigned short*)(ws + 12800000);   // 12.8MB
    unsigned short* h  = (unsigned short*)(ws + 25600000);   // 12.8MB
    unsigned short* hl = (unsigned short*)(ws + 38400000);   // 100000x32 bf16, 6.4MB
    unsigned short* hr = (unsigned short*)(ws + 44800000);   // 6.4MB
    int* csr_src = (int*)(ws + 51200000);                    // 2.4MB
    int* deg     = (int*)(ws + 53600000);
    int* tmp     = (int*)(ws + 53600000 + 401408);
    int* row_ptr = (int*)(ws + 53600000 + 2 * 401408);
    int* cursor  = (int*)(ws + 53600000 + 2 * 401408 + 400016);
    int* bs      = (int*)(ws + 53600000 + 2 * 401408 + 400016 + 400000);
    int* boff    = (int*)(ws + 53600000 + 2 * 401408 + 400016 + 400000 + 512);

    // ---- CSR build ----
    hipMemsetAsync(deg, 0, N_PAD * sizeof(int), stream);
    hist_deg<<<(N_EDGES + 255) / 256, 256, 0, stream>>>(ei, deg);
    scan_blocks<<<NB1, 256, 0, stream>>>(deg, tmp, bs);
    scan_sums<<<1, 128, 0, stream>>>(bs, boff);
    scan_add<<<NB1, 256, 0, stream>>>(tmp, deg, boff, row_ptr, cursor);
    build_csr<<<(N_EDGES + 255) / 256, 256, 0, stream>>>(ei, cursor, csr_src);

    constexpr int GEMM_BLOCKS = (N_NODES / 32 + 3 + 1) / 4 + 1;  // waves=3125 -> 782 blocks
    // ---- Layer 1: project (128 -> 64||64), gather-mean + relu ----
    gemm_direct<128, 64, false><<<GEMM_BLOCKS, 256, 0, stream>>>(x, w1l, w1r, xl, xr);
    gather_agg<64, true, true><<<(N_NODES * 8 + 255) / 256, 256, 0, stream>>>(
        xl, row_ptr, csr_src, b1l, xr, h);

    // ---- Layer 2: project (64 -> 32||32), gather-mean ----
    gemm_direct<64, 32, true><<<GEMM_BLOCKS, 256, 0, stream>>>(h, w2l, w2r, hl, hr);
    gather_agg<32, false, false><<<(N_NODES * 4 + 255) / 256, 256, 0, stream>>>(
        hl, row_ptr, csr_src, b2l, hr, out);
}

// Round 5
// 153.501 us; speedup vs baseline: 6.3660x; 1.0690x over previous
//
#include <hip/hip_runtime.h>

#define N_NODES 100000
#define N_EDGES 600000
#define N_PAD   100352      // N_NODES rounded up to 1024 (scan tiles)
#define NB1     98          // ceil(N_NODES/1024)
#define N_WAVES 3125        // N_NODES / 32 exactly

typedef __bf16 bf16x8 __attribute__((ext_vector_type(8)));
typedef float  f32x4  __attribute__((ext_vector_type(4)));
typedef unsigned short u16x8 __attribute__((ext_vector_type(8)));
typedef unsigned short u16x4 __attribute__((ext_vector_type(4)));

__device__ inline unsigned short f2bf(float f) {
    __bf16 h = (__bf16)f;                 // RNE via v_cvt
    return __builtin_bit_cast(unsigned short, h);
}
__device__ inline float bf2f(unsigned short u) {
    return __builtin_bit_cast(float, ((unsigned)u) << 16);
}

// load 8 consecutive f32 and convert to bf16x8
__device__ inline bf16x8 ldfrag_f32(const float* p) {
    float4 u = *(const float4*)p;
    float4 w = *(const float4*)(p + 4);
    u16x8 o;
    o[0]=f2bf(u.x); o[1]=f2bf(u.y); o[2]=f2bf(u.z); o[3]=f2bf(u.w);
    o[4]=f2bf(w.x); o[5]=f2bf(w.y); o[6]=f2bf(w.z); o[7]=f2bf(w.w);
    return __builtin_bit_cast(bf16x8, o);
}
__device__ inline bf16x8 ldfrag_bf16(const unsigned short* p) {
    u16x8 v = *(const u16x8*)p;
    return __builtin_bit_cast(bf16x8, v);
}

// ---------------------------------------------------------------------------
// One-time weight conversion: wbf1 = [w1l;w1r] as [128][128] bf16,
//                             wbf2 = [w2l;w2r] as [64][64]  bf16
// ---------------------------------------------------------------------------
__global__ __launch_bounds__(256) void convert_w(
    const float* __restrict__ w1l, const float* __restrict__ w1r,
    const float* __restrict__ w2l, const float* __restrict__ w2r,
    unsigned short* __restrict__ wbf1, unsigned short* __restrict__ wbf2)
{
    int i = blockIdx.x * 256 + threadIdx.x;   // grid covers 20480
    if (i < 16384) {
        int row = i >> 7, k = i & 127;
        float v = (row < 64) ? w1l[(row << 7) + k] : w1r[((row - 64) << 7) + k];
        wbf1[i] = f2bf(v);
    } else {
        int j = i - 16384;                    // [0, 4096)
        int row = j >> 6, k = j & 63;
        float v = (row < 32) ? w2l[(row << 6) + k] : w2r[((row - 32) << 6) + k];
        wbf2[j] = f2bf(v);
    }
}

// ---------------------------------------------------------------------------
// LDS-free swapped-operand MFMA dual GEMM.
// D = mfma(W_frag, x_frag): D rows = output feats, cols = nodes ->
// each lane packs 4 consecutive feats of one node into an 8B store.
// Wave owns 32 nodes; W ([2F][K] bf16, <=32KB) is L1-resident.
// ---------------------------------------------------------------------------
template<int K, int F, bool A_BF16>
__global__ __launch_bounds__(256) void gemm_swapped(
    const void* __restrict__ xv,
    const unsigned short* __restrict__ wbf,   // [2F][K] bf16
    unsigned short* __restrict__ outl,
    unsigned short* __restrict__ outr)
{
    constexpr int NT  = 2 * F / 16;  // feat tiles
    constexpr int NKT = K / 32;      // k-steps

    const int tid = threadIdx.x;
    const int wid = (blockIdx.x * 256 + tid) >> 6;
    if (wid >= N_WAVES) return;
    const int l     = tid & 63;
    const int lrow  = l & 15;
    const int ksub  = (l >> 4) * 8;        // k element offset within 32-k step
    const int nbase = wid * 32;            // exact: no tail (100000 = 3125*32)

    const float*          xf  = (const float*)xv;
    const unsigned short* x16 = (const unsigned short*)xv;

    f32x4 acc[2][NT];
    #pragma unroll
    for (int nf = 0; nf < 2; ++nf)
        #pragma unroll
        for (int mt = 0; mt < NT; ++mt) acc[nf][mt] = (f32x4){0.f,0.f,0.f,0.f};

    #pragma unroll
    for (int kt = 0; kt < NKT; ++kt) {
        const int kc = kt * 32 + ksub;
        // B-operand: x rows (nodes nbase+lrow, nbase+16+lrow)
        bf16x8 b0 = A_BF16 ? ldfrag_bf16(x16 + (nbase + lrow) * K + kc)
                           : ldfrag_f32 (xf  + (nbase + lrow) * K + kc);
        bf16x8 b1 = A_BF16 ? ldfrag_bf16(x16 + (nbase + 16 + lrow) * K + kc)
                           : ldfrag_f32 (xf  + (nbase + 16 + lrow) * K + kc);
        #pragma unroll
        for (int mt = 0; mt < NT; ++mt) {
            // A-operand: W rows (feats mt*16+lrow), single 16B load, no cvt
            bf16x8 a = ldfrag_bf16(wbf + (mt * 16 + lrow) * K + kc);
            acc[0][mt] = __builtin_amdgcn_mfma_f32_16x16x32_bf16(a, b0, acc[0][mt], 0, 0, 0);
            acc[1][mt] = __builtin_amdgcn_mfma_f32_16x16x32_bf16(a, b1, acc[1][mt], 0, 0, 0);
        }
    }

    // D: col = lane&15 (node), row = (lane>>4)*4 + reg (feat)
    const int fgrp = (l >> 4) * 4;
    #pragma unroll
    for (int nf = 0; nf < 2; ++nf) {
        const int node = nbase + nf * 16 + lrow;
        #pragma unroll
        for (int mt = 0; mt < NT; ++mt) {
            u16x4 p;
            p[0] = f2bf(acc[nf][mt][0]);
            p[1] = f2bf(acc[nf][mt][1]);
            p[2] = f2bf(acc[nf][mt][2]);
            p[3] = f2bf(acc[nf][mt][3]);
            const int feat = mt * 16 + fgrp;
            if (mt * 16 < F) *(u16x4*)&outl[node * F + feat]       = p;
            else             *(u16x4*)&outr[node * F + (feat - F)] = p;
        }
    }
}

// ---------------------------------------------------------------------------
// CSR build: degree histogram -> scan -> edge bucketing
// ---------------------------------------------------------------------------
__global__ __launch_bounds__(256) void hist_deg(const int* __restrict__ ei,
                                                int* __restrict__ deg)
{
    int e = blockIdx.x * 256 + threadIdx.x;
    if (e < N_EDGES) atomicAdd(&deg[ei[N_EDGES + e]], 1);
}

__global__ __launch_bounds__(256) void scan_blocks(const int* __restrict__ deg,
                                                   int* __restrict__ tmp,
                                                   int* __restrict__ bs)
{
    __shared__ int s[256];
    int b = blockIdx.x, tid = threadIdx.x;
    int i = b * 1024 + tid * 4;
    int4 v = *(const int4*)&deg[i];
    int p0 = v.x, p1 = p0 + v.y, p2 = p1 + v.z, p3 = p2 + v.w;
    s[tid] = p3;
    __syncthreads();
    for (int off = 1; off < 256; off <<= 1) {
        int t = (tid >= off) ? s[tid - off] : 0;
        __syncthreads();
        s[tid] += t;
        __syncthreads();
    }
    int excl = s[tid] - p3;
    int4 o; o.x = excl + p0; o.y = excl + p1; o.z = excl + p2; o.w = excl + p3;
    *(int4*)&tmp[i] = o;
    if (tid == 255) bs[b] = s[255];
}

__global__ __launch_bounds__(128) void scan_sums(int* __restrict__ bs,
                                                 int* __restrict__ boff)
{
    __shared__ int s[128];
    int tid = threadIdx.x;
    s[tid] = (tid < NB1) ? bs[tid] : 0;
    __syncthreads();
    for (int off = 1; off < 128; off <<= 1) {
        int t = (tid >= off) ? s[tid - off] : 0;
        __syncthreads();
        s[tid] += t;
        __syncthreads();
    }
    if (tid < NB1) boff[tid] = s[tid];
}

__global__ __launch_bounds__(256) void scan_add(const int* __restrict__ tmp,
                                                const int* __restrict__ deg,
                                                const int* __restrict__ boff,
                                                int* __restrict__ row_ptr,
                                                int* __restrict__ cursor)
{
    int b = blockIdx.x, tid = threadIdx.x;
    int i = b * 1024 + tid * 4;
    int off = (b > 0) ? boff[b - 1] : 0;
    int4 t = *(const int4*)&tmp[i];
    int4 d = *(const int4*)&deg[i];
    if (b == 0 && tid == 0) row_ptr[0] = 0;
    if (i + 0 < N_NODES) { row_ptr[i + 1] = t.x + off; cursor[i + 0] = t.x + off - d.x; }
    if (i + 1 < N_NODES) { row_ptr[i + 2] = t.y + off; cursor[i + 1] = t.y + off - d.y; }
    if (i + 2 < N_NODES) { row_ptr[i + 3] = t.z + off; cursor[i + 2] = t.z + off - d.z; }
    if (i + 3 < N_NODES) { row_ptr[i + 4] = t.w + off; cursor[i + 3] = t.w + off - d.w; }
}

__global__ __launch_bounds__(256) void build_csr(const int* __restrict__ ei,
                                                 int* __restrict__ cursor,
                                                 int* __restrict__ csr_src)
{
    int e = blockIdx.x * 256 + threadIdx.x;
    if (e >= N_EDGES) return;
    int d = ei[N_EDGES + e];
    int pos = atomicAdd(&cursor[d], 1);
    csr_src[pos] = ei[e];
}

// ---------------------------------------------------------------------------
// Gather-aggregate + fused epilogue (bf16 feat/right, bf16 or f32 out):
// out[n] = [relu]( (sum_{s in csr[n]} feat[s]) / max(deg,1) + bias + right[n] )
// ---------------------------------------------------------------------------
template<int F, bool RELU, bool OUT_BF16>
__global__ __launch_bounds__(256) void gather_agg(
    const unsigned short* __restrict__ feat,
    const int* __restrict__ row_ptr,
    const int* __restrict__ csr_src,
    const float* __restrict__ bias,
    const unsigned short* __restrict__ right,
    void* __restrict__ outv)
{
    constexpr int C8 = F / 8;
    int t = blockIdx.x * 256 + threadIdx.x;
    int n = t / C8;
    int q = t - n * C8;
    if (n >= N_NODES) return;
    int beg = row_ptr[n], end = row_ptr[n + 1];

    float acc[8] = {0.f,0.f,0.f,0.f,0.f,0.f,0.f,0.f};
    for (int i = beg; i < end; ++i) {
        int s = csr_src[i];
        u16x8 v = *(const u16x8*)&feat[s * F + 8 * q];
        #pragma unroll
        for (int j = 0; j < 8; ++j) acc[j] += bf2f(v[j]);
    }
    float inv = 1.0f / (float)max(end - beg, 1);
    u16x8 rv = *(const u16x8*)&right[n * F + 8 * q];
    float4 b0 = *(const float4*)&bias[8 * q];
    float4 b1 = *(const float4*)&bias[8 * q + 4];
    float bb[8] = {b0.x,b0.y,b0.z,b0.w,b1.x,b1.y,b1.z,b1.w};

    float o[8];
    #pragma unroll
    for (int j = 0; j < 8; ++j) {
        o[j] = fmaf(acc[j], inv, bb[j]) + bf2f(rv[j]);
        if (RELU) o[j] = fmaxf(o[j], 0.f);
    }
    if (OUT_BF16) {
        u16x8 ov;
        #pragma unroll
        for (int j = 0; j < 8; ++j) ov[j] = f2bf(o[j]);
        *(u16x8*)((unsigned short*)outv + n * F + 8 * q) = ov;
    } else {
        float* op = (float*)outv + n * F + 8 * q;
        *(float4*)op       = make_float4(o[0], o[1], o[2], o[3]);
        *(float4*)(op + 4) = make_float4(o[4], o[5], o[6], o[7]);
    }
}

extern "C" void kernel_launch(void* const* d_in, const int* in_sizes, int n_in,
                              void* d_out, int out_size, void* d_ws, size_t ws_size,
                              hipStream_t stream)
{
    const float* x   = (const float*)d_in[0];
    const int*   ei  = (const int*)d_in[1];   // int32 (JAX x64 disabled)
    const float* w1l = (const float*)d_in[2];
    const float* b1l = (const float*)d_in[3];
    const float* w1r = (const float*)d_in[4];
    const float* w2l = (const float*)d_in[5];
    const float* b2l = (const float*)d_in[6];
    const float* w2r = (const float*)d_in[7];
    float* out = (float*)d_out;

    char* ws = (char*)d_ws;
    unsigned short* xl = (unsigned short*)(ws + 0);          // 100000x64 bf16
    unsigned short* xr = (unsigned short*)(ws + 12800000);
    unsigned short* h  = (unsigned short*)(ws + 25600000);
    unsigned short* hl = (unsigned short*)(ws + 38400000);   // 100000x32 bf16
    unsigned short* hr = (unsigned short*)(ws + 44800000);
    int* csr_src = (int*)(ws + 51200000);
    int* deg     = (int*)(ws + 53600000);
    int* tmp     = (int*)(ws + 53600000 + 401408);
    int* row_ptr = (int*)(ws + 53600000 + 2 * 401408);
    int* cursor  = (int*)(ws + 53600000 + 2 * 401408 + 400016);
    int* bs      = (int*)(ws + 53600000 + 2 * 401408 + 400016 + 400000);
    int* boff    = (int*)(ws + 53600000 + 2 * 401408 + 400016 + 400000 + 512);
    unsigned short* wbf1 = (unsigned short*)(ws + 56000000); // [128][128] bf16
    unsigned short* wbf2 = (unsigned short*)(ws + 56100000); // [64][64]  bf16

    // ---- weight conversion (tiny) + CSR build ----
    convert_w<<<80, 256, 0, stream>>>(w1l, w1r, w2l, w2r, wbf1, wbf2);
    hipMemsetAsync(deg, 0, N_PAD * sizeof(int), stream);
    hist_deg<<<(N_EDGES + 255) / 256, 256, 0, stream>>>(ei, deg);
    scan_blocks<<<NB1, 256, 0, stream>>>(deg, tmp, bs);
    scan_sums<<<1, 128, 0, stream>>>(bs, boff);
    scan_add<<<NB1, 256, 0, stream>>>(tmp, deg, boff, row_ptr, cursor);
    build_csr<<<(N_EDGES + 255) / 256, 256, 0, stream>>>(ei, cursor, csr_src);

    constexpr int GEMM_BLOCKS = (N_WAVES + 3) / 4;  // 782
    // ---- Layer 1: project (128 -> 64||64), gather-mean + relu ----
    gemm_swapped<128, 64, false><<<GEMM_BLOCKS, 256, 0, stream>>>(x, wbf1, xl, xr);
    gather_agg<64, true, true><<<(N_NODES * 8 + 255) / 256, 256, 0, stream>>>(
        xl, row_ptr, csr_src, b1l, xr, h);

    // ---- Layer 2: project (64 -> 32||32), gather-mean ----
    gemm_swapped<64, 32, true><<<GEMM_BLOCKS, 256, 0, stream>>>(h, wbf2, hl, hr);
    gather_agg<32, false, false><<<(N_NODES * 4 + 255) / 256, 256, 0, stream>>>(
        hl, row_ptr, csr_src, b2l, hr, out);
}

// Round 6
// 136.543 us; speedup vs baseline: 7.1566x; 1.1242x over previous
//
#include <hip/hip_runtime.h>

#define N_NODES 100000
#define N_EDGES 600000
#define N_PAD   100352      // N_NODES rounded to 1024 (scan tiles)
#define NB1     98          // N_PAD / 1024
#define G1_WAVES 6250       // N_NODES / 16 exactly
#define G1_BLOCKS 1563      // ceil(6250/4)
#define HIST_BLOCKS 2344    // ceil(600000/256)
#define MID_BLOCKS 3125     // N_NODES / 32 exactly

typedef __bf16 bf16x8 __attribute__((ext_vector_type(8)));
typedef float  f32x4  __attribute__((ext_vector_type(4)));
typedef unsigned short u16x8 __attribute__((ext_vector_type(8)));
typedef unsigned short u16x4 __attribute__((ext_vector_type(4)));

__device__ inline unsigned short f2bf(float f) {
    __bf16 h = (__bf16)f;
    return __builtin_bit_cast(unsigned short, h);
}
__device__ inline float bf2f(unsigned short u) {
    return __builtin_bit_cast(float, ((unsigned)u) << 16);
}
__device__ inline bf16x8 ldfrag_f32(const float* p) {
    float4 u = *(const float4*)p;
    float4 w = *(const float4*)(p + 4);
    u16x8 o;
    o[0]=f2bf(u.x); o[1]=f2bf(u.y); o[2]=f2bf(u.z); o[3]=f2bf(u.w);
    o[4]=f2bf(w.x); o[5]=f2bf(w.y); o[6]=f2bf(w.z); o[7]=f2bf(w.w);
    return __builtin_bit_cast(bf16x8, o);
}
__device__ inline bf16x8 ldfrag_bf16(const unsigned short* p) {
    u16x8 v = *(const u16x8*)p;
    return __builtin_bit_cast(bf16x8, v);
}

// ---------------------------------------------------------------------------
// prep: zero deg + gbase, convert W1 ([128][128]) and W2 ([64][64]) to bf16
// grid = 392 blocks x 256 = 100352 threads
// ---------------------------------------------------------------------------
__global__ __launch_bounds__(256) void prep(
    const float* __restrict__ w1l, const float* __restrict__ w1r,
    const float* __restrict__ w2l, const float* __restrict__ w2r,
    unsigned short* __restrict__ wbf1, unsigned short* __restrict__ wbf2,
    int* __restrict__ deg, int* __restrict__ gbase)
{
    int i = blockIdx.x * 256 + threadIdx.x;
    if (i < N_PAD) deg[i] = 0;
    if (i == 0) gbase[0] = 0;
    if (i < 16384) {
        int row = i >> 7, k = i & 127;
        float v = (row < 64) ? w1l[(row << 7) + k] : w1r[((row - 64) << 7) + k];
        wbf1[i] = f2bf(v);
    } else if (i < 20480) {
        int j = i - 16384;
        int row = j >> 6, k = j & 63;
        float v = (row < 32) ? w2l[(row << 6) + k] : w2r[((row - 32) << 6) + k];
        wbf2[j] = f2bf(v);
    }
}

// ---------------------------------------------------------------------------
// front: blocks [0,G1_BLOCKS) = layer-1 GEMM (16 nodes/wave, swapped MFMA);
//        blocks [G1_BLOCKS, +HIST_BLOCKS) = degree histogram.
// ---------------------------------------------------------------------------
__global__ __launch_bounds__(256) void front(
    const float* __restrict__ x,
    const unsigned short* __restrict__ wbf1,   // [128][128] bf16
    const int* __restrict__ ei,
    unsigned short* __restrict__ xl,
    unsigned short* __restrict__ xr,
    int* __restrict__ deg)
{
    const int b   = blockIdx.x;
    const int tid = threadIdx.x;

    if (b >= G1_BLOCKS) {
        int e = (b - G1_BLOCKS) * 256 + tid;
        if (e < N_EDGES) atomicAdd(&deg[ei[N_EDGES + e]], 1);
        return;
    }

    const int wid = b * 4 + (tid >> 6);
    if (wid >= G1_WAVES) return;
    const int l    = tid & 63;
    const int lrow = l & 15;
    const int hi   = l >> 4;
    const int ksub = hi * 8;
    const int node = wid * 16 + lrow;          // < 100000 always

    f32x4 acc[8];
    #pragma unroll
    for (int mt = 0; mt < 8; ++mt) acc[mt] = (f32x4){0.f,0.f,0.f,0.f};

    #pragma unroll
    for (int kt = 0; kt < 4; ++kt) {
        const int kc = kt * 32 + ksub;
        bf16x8 bfrag = ldfrag_f32(x + node * 128 + kc);   // x row (node), cvt in reg
        #pragma unroll
        for (int mt = 0; mt < 8; ++mt) {
            bf16x8 a = ldfrag_bf16(wbf1 + (mt * 16 + lrow) * 128 + kc);  // L1-resident
            acc[mt] = __builtin_amdgcn_mfma_f32_16x16x32_bf16(a, bfrag, acc[mt], 0, 0, 0);
        }
    }

    // D: col = lane&15 -> node, row = hi*4 + r -> feat
    const int node_c = wid * 16 + lrow;
    const int fgrp   = hi * 4;
    #pragma unroll
    for (int mt = 0; mt < 8; ++mt) {
        u16x4 p;
        p[0] = f2bf(acc[mt][0]); p[1] = f2bf(acc[mt][1]);
        p[2] = f2bf(acc[mt][2]); p[3] = f2bf(acc[mt][3]);
        const int feat = mt * 16 + fgrp;
        if (mt < 4) *(u16x4*)&xl[node_c * 64 + feat]        = p;
        else        *(u16x4*)&xr[node_c * 64 + (feat - 64)] = p;
    }
}

// ---------------------------------------------------------------------------
// scan: per-block scan of deg + atomic global base -> start[], cursor[]
// (cross-block order nondeterministic; per-node bucket contents unchanged)
// ---------------------------------------------------------------------------
__global__ __launch_bounds__(256) void scan_atomic(
    const int* __restrict__ deg, int* __restrict__ gbase,
    int* __restrict__ start, int* __restrict__ cursor)
{
    __shared__ int s[256];
    __shared__ int base_s;
    int b = blockIdx.x, tid = threadIdx.x;
    int i = b * 1024 + tid * 4;
    int4 v = *(const int4*)&deg[i];
    int p0 = v.x, p1 = p0 + v.y, p2 = p1 + v.z, p3 = p2 + v.w;
    s[tid] = p3;
    __syncthreads();
    for (int off = 1; off < 256; off <<= 1) {
        int t = (tid >= off) ? s[tid - off] : 0;
        __syncthreads();
        s[tid] += t;
        __syncthreads();
    }
    if (tid == 255) base_s = atomicAdd(gbase, s[255]);
    int excl = s[tid] - p3;
    __syncthreads();
    int e0 = base_s + excl;
    int e1 = e0 + v.x, e2 = e1 + v.y, e3 = e2 + v.z;
    if (i + 0 < N_NODES) { start[i + 0] = e0; cursor[i + 0] = e0; }
    if (i + 1 < N_NODES) { start[i + 1] = e1; cursor[i + 1] = e1; }
    if (i + 2 < N_NODES) { start[i + 2] = e2; cursor[i + 2] = e2; }
    if (i + 3 < N_NODES) { start[i + 3] = e3; cursor[i + 3] = e3; }
}

__global__ __launch_bounds__(256) void build_csr(const int* __restrict__ ei,
                                                 int* __restrict__ cursor,
                                                 int* __restrict__ csr_src)
{
    int e = blockIdx.x * 256 + threadIdx.x;
    if (e >= N_EDGES) return;
    int d = ei[N_EDGES + e];
    int pos = atomicAdd(&cursor[d], 1);
    csr_src[pos] = ei[e];
}

// ---------------------------------------------------------------------------
// mid: fused gather1(+bias+right+relu) -> LDS h-tile (32 nodes) -> gemm2 MFMA
// block = 256 threads = 4 waves, owns 32 nodes (3125 blocks, exact).
// Gather: 8 threads/node, each one u16x8 chunk. h never touches HBM.
// ---------------------------------------------------------------------------
__global__ __launch_bounds__(256) void mid(
    const unsigned short* __restrict__ xl,
    const unsigned short* __restrict__ xr,
    const int* __restrict__ start,
    const int* __restrict__ deg,
    const int* __restrict__ csr_src,
    const float* __restrict__ b1l,
    const unsigned short* __restrict__ wbf2,   // [64][64] bf16
    unsigned short* __restrict__ hl,
    unsigned short* __restrict__ hr)
{
    __shared__ unsigned short hs[32 * 64];     // 4KB, swizzled rows of 128B

    const int tid = threadIdx.x;
    const int nd  = tid >> 3;                  // local node 0..31
    const int q   = tid & 7;                   // feat chunk 0..7
    const int node = blockIdx.x * 32 + nd;     // always < N_NODES

    const int beg = start[node];
    const int dg  = deg[node];

    float acc[8] = {0.f,0.f,0.f,0.f,0.f,0.f,0.f,0.f};
    for (int i = 0; i < dg; ++i) {
        int s = csr_src[beg + i];
        u16x8 v = *(const u16x8*)&xl[s * 64 + 8 * q];
        #pragma unroll
        for (int j = 0; j < 8; ++j) acc[j] += bf2f(v[j]);
    }
    const float inv = 1.0f / (float)max(dg, 1);
    u16x8 rv = *(const u16x8*)&xr[node * 64 + 8 * q];
    float4 b0 = *(const float4*)&b1l[8 * q];
    float4 b1 = *(const float4*)&b1l[8 * q + 4];
    float bb[8] = {b0.x,b0.y,b0.z,b0.w,b1.x,b1.y,b1.z,b1.w};
    u16x8 hv;
    #pragma unroll
    for (int j = 0; j < 8; ++j) {
        float o = fmaf(acc[j], inv, bb[j]) + bf2f(rv[j]);
        hv[j] = f2bf(fmaxf(o, 0.f));
    }
    *(u16x8*)((char*)hs + nd * 128 + ((q * 16) ^ ((nd & 7) << 4))) = hv;
    __syncthreads();

    // gemm2: wave wv handles feat tile wv*16; B = h nodes from LDS
    const int wv   = tid >> 6;
    const int l    = tid & 63;
    const int lrow = l & 15;
    const int hi   = l >> 4;

    f32x4 a0 = (f32x4){0.f,0.f,0.f,0.f};
    f32x4 a1 = (f32x4){0.f,0.f,0.f,0.f};
    #pragma unroll
    for (int kt = 0; kt < 2; ++kt) {
        const int kin = kt * 64 + hi * 16;     // k byte offset within row
        bf16x8 bf0 = __builtin_bit_cast(bf16x8, *(const u16x8*)
            ((const char*)hs + lrow * 128 + (kin ^ ((lrow & 7) << 4))));
        bf16x8 bf1 = __builtin_bit_cast(bf16x8, *(const u16x8*)
            ((const char*)hs + (16 + lrow) * 128 + (kin ^ ((lrow & 7) << 4))));
        bf16x8 a = ldfrag_bf16(wbf2 + (wv * 16 + lrow) * 64 + kt * 32 + hi * 8);
        a0 = __builtin_amdgcn_mfma_f32_16x16x32_bf16(a, bf0, a0, 0, 0, 0);
        a1 = __builtin_amdgcn_mfma_f32_16x16x32_bf16(a, bf1, a1, 0, 0, 0);
    }

    // D: col = lane&15 -> local node (0..15 / 16..31), row = hi*4+r -> feat
    const int n0 = blockIdx.x * 32 + lrow;
    const int n1 = n0 + 16;
    const int feat = wv * 16 + hi * 4;
    u16x4 p0, p1;
    p0[0]=f2bf(a0[0]); p0[1]=f2bf(a0[1]); p0[2]=f2bf(a0[2]); p0[3]=f2bf(a0[3]);
    p1[0]=f2bf(a1[0]); p1[1]=f2bf(a1[1]); p1[2]=f2bf(a1[2]); p1[3]=f2bf(a1[3]);
    if (wv < 2) {
        *(u16x4*)&hl[n0 * 32 + feat] = p0;
        *(u16x4*)&hl[n1 * 32 + feat] = p1;
    } else {
        *(u16x4*)&hr[n0 * 32 + (feat - 32)] = p0;
        *(u16x4*)&hr[n1 * 32 + (feat - 32)] = p1;
    }
}

// ---------------------------------------------------------------------------
// gather2: out[n] = (sum hl[s]) / max(deg,1) + b2 + hr[n]   (f32 out)
// ---------------------------------------------------------------------------
__global__ __launch_bounds__(256) void gather2(
    const unsigned short* __restrict__ hl,
    const int* __restrict__ start,
    const int* __restrict__ deg,
    const int* __restrict__ csr_src,
    const float* __restrict__ b2l,
    const unsigned short* __restrict__ hr,
    float* __restrict__ out)
{
    int t = blockIdx.x * 256 + threadIdx.x;
    int n = t >> 2;
    int q = t & 3;
    if (n >= N_NODES) return;
    int beg = start[n], dg = deg[n];

    float acc[8] = {0.f,0.f,0.f,0.f,0.f,0.f,0.f,0.f};
    for (int i = 0; i < dg; ++i) {
        int s = csr_src[beg + i];
        u16x8 v = *(const u16x8*)&hl[s * 32 + 8 * q];
        #pragma unroll
        for (int j = 0; j < 8; ++j) acc[j] += bf2f(v[j]);
    }
    float inv = 1.0f / (float)max(dg, 1);
    u16x8 rv = *(const u16x8*)&hr[n * 32 + 8 * q];
    float4 b0 = *(const float4*)&b2l[8 * q];
    float4 b1 = *(const float4*)&b2l[8 * q + 4];
    float bb[8] = {b0.x,b0.y,b0.z,b0.w,b1.x,b1.y,b1.z,b1.w};
    float o[8];
    #pragma unroll
    for (int j = 0; j < 8; ++j)
        o[j] = fmaf(acc[j], inv, bb[j]) + bf2f(rv[j]);
    float* op = out + n * 32 + 8 * q;
    *(float4*)op       = make_float4(o[0], o[1], o[2], o[3]);
    *(float4*)(op + 4) = make_float4(o[4], o[5], o[6], o[7]);
}

extern "C" void kernel_launch(void* const* d_in, const int* in_sizes, int n_in,
                              void* d_out, int out_size, void* d_ws, size_t ws_size,
                              hipStream_t stream)
{
    const float* x   = (const float*)d_in[0];
    const int*   ei  = (const int*)d_in[1];   // int32 (JAX x64 disabled)
    const float* w1l = (const float*)d_in[2];
    const float* b1l = (const float*)d_in[3];
    const float* w1r = (const float*)d_in[4];
    const float* w2l = (const float*)d_in[5];
    const float* b2l = (const float*)d_in[6];
    const float* w2r = (const float*)d_in[7];
    float* out = (float*)d_out;

    char* ws = (char*)d_ws;
    unsigned short* xl   = (unsigned short*)(ws + 0);          // 100000x64 bf16
    unsigned short* xr   = (unsigned short*)(ws + 12800000);
    unsigned short* hl   = (unsigned short*)(ws + 25600000);   // 100000x32 bf16
    unsigned short* hr   = (unsigned short*)(ws + 32000000);
    int*   csr_src = (int*)(ws + 38400000);                    // 2.4MB
    int*   deg     = (int*)(ws + 40800000);                    // N_PAD
    int*   start   = (int*)(ws + 41201408);
    int*   cursor  = (int*)(ws + 41601408);
    unsigned short* wbf1 = (unsigned short*)(ws + 42001408);   // [128][128]
    unsigned short* wbf2 = (unsigned short*)(ws + 42034176);   // [64][64]
    int*   gbase   = (int*)(ws + 42042368);

    // 1. prep: zero deg/gbase + convert weights
    prep<<<392, 256, 0, stream>>>(w1l, w1r, w2l, w2r, wbf1, wbf2, deg, gbase);
    // 2. front: layer-1 GEMM + degree histogram (independent, merged)
    front<<<G1_BLOCKS + HIST_BLOCKS, 256, 0, stream>>>(x, wbf1, ei, xl, xr, deg);
    // 3. scan (atomic block base)
    scan_atomic<<<NB1, 256, 0, stream>>>(deg, gbase, start, cursor);
    // 4. bucket edges
    build_csr<<<HIST_BLOCKS, 256, 0, stream>>>(ei, cursor, csr_src);
    // 5. fused gather1 + epilogue + gemm2 (h stays in LDS)
    mid<<<MID_BLOCKS, 256, 0, stream>>>(xl, xr, start, deg, csr_src, b1l, wbf2, hl, hr);
    // 6. gather2 + epilogue -> out
    gather2<<<(N_NODES * 4 + 255) / 256, 256, 0, stream>>>(hl, start, deg, csr_src, b2l, hr, out);
}